// Round 6
// baseline (192.078 us; speedup 1.0000x reference)
//
#include <hip/hip_runtime.h>
#include <hip/hip_bf16.h>
#include <hip/hip_fp16.h>

// NNConv R19: XCD-local L2 atomics. R18 post-mortem: occupancy 34->49% bought
// ~0 (85->83us) -- per pre-commit, the memory-side atomic unit is the wall
// (12.8M device-scope f32 atomics ~= 50-85us serialized; WRITE_SIZE rose with
// concurrency = partial-line thrash at the coherent point). Fix: per-XCD
// partial sum buffers (8 x 3.2MB, each fits the XCD's private 4MB L2),
// selected by s_getreg(HW_REG_XCC_ID) (m09), epilogue adds issued as raw
// global_atomic_add_f32 WITHOUT sc bits (inline asm) -> execute in the local
// TCC at L2 speed, parallel across 8 XCDs x 16 channels. Coherence: strict
// partition by real XCC_ID (only XCD i touches buffer i); kernel-end release
// writes back dirty L2; node_k's kernel-begin acquire invalidates, then sums
// the 8 partials. deg stays a device-scope int atomic (0.8M ops, minor).
// Falsifier: edge WRITE 87.4 -> ~30MB = atomics went local. ws 24.6MB.

#define N_NODES 50000
#define N_EDGES 800000
#define IN_D    16
#define OUT_D   16
#define HID_D   32
#define KTILES  17
#define NXCD    8
#define NBLK_E  (N_EDGES / 256)            // 3125, exact
#define NBLK_N  (N_NODES * OUT_D / 256)    // 3125, exact
#define BLOB_BYTES 20480                   // 20 x 1KB chunks
#define BLOB_W1    17408                   // s_B image [0,17408)
#define BLOB_B1    19456                   // w1 [17408,19456), b1 [19456,19584)

#define SUM_ELEMS  ((size_t)N_NODES * 16)  // 800000 f32 per partial = 3.2MB

// ws layout (byte offsets)
#define WS_SUM   20480                                     // 8 x 3.2MB partials
#define WS_DEG   (20480 + NXCD * 3200000)                  // 25,620,480: N ints
#define WS_NEED  ((size_t)WS_DEG + (size_t)N_NODES * 4)    // ~24.6MB

typedef __attribute__((ext_vector_type(8))) _Float16 hfrag8;
typedef __attribute__((ext_vector_type(4))) float f32x4;

__device__ __forceinline__ void fma4(float a, const float4 w, float4& m) {
    m.x = fmaf(a, w.x, m.x);
    m.y = fmaf(a, w.y, m.y);
    m.z = fmaf(a, w.z, m.z);
    m.w = fmaf(a, w.w, m.w);
}
__device__ __forceinline__ int clampn(int v) {
    return v < 0 ? 0 : (v >= N_NODES ? N_NODES - 1 : v);
}
__device__ __forceinline__ void gload_lds16(const void* g, void* l) {
    __builtin_amdgcn_global_load_lds(
        (const __attribute__((address_space(1))) unsigned int*)g,
        (__attribute__((address_space(3))) unsigned int*)l,
        16, 0, 0);
}
// XCD-scope f32 atomic add: no sc0/sc1 -> executes in the local XCD's TCC (L2).
// ONLY correct when the target buffer is touched exclusively by this XCD.
__device__ __forceinline__ void xcdAtomicAdd(float* p, float v) {
    asm volatile("global_atomic_add_f32 %0, %1, off" :: "v"(p), "v"(v) : "memory");
}

// ---------------- one-block setup: build {s_B f16 image, w1, b1} blob ----------------

__global__ __launch_bounds__(256) void setup_k(
    const float* __restrict__ w1,
    const float* __restrict__ b1,
    const float* __restrict__ w2,
    const float* __restrict__ b2,
    unsigned char* __restrict__ blob)
{
    const int t = threadIdx.x;
    __half* bp = reinterpret_cast<__half*>(blob);
    for (int r = t; r < KTILES * 32; r += 256) {
        const int tile = r >> 5, q = (r >> 3) & 3, j = r & 7;
        const int base = ((tile * 4 + q) * 16) * 8 + j;
        float vals[16];
        if (r < 512) {
            const float4* wr = reinterpret_cast<const float4*>(w2) + r * 4;
            float4 v0 = wr[0], v1 = wr[1], v2 = wr[2], v3 = wr[3];
            vals[0]=v0.x; vals[1]=v0.y; vals[2]=v0.z; vals[3]=v0.w;
            vals[4]=v1.x; vals[5]=v1.y; vals[6]=v1.z; vals[7]=v1.w;
            vals[8]=v2.x; vals[9]=v2.y; vals[10]=v2.z; vals[11]=v2.w;
            vals[12]=v3.x; vals[13]=v3.y; vals[14]=v3.z; vals[15]=v3.w;
        } else if (r < 528) {
            const float4* br = reinterpret_cast<const float4*>(b2) + (r - 512) * 4;
            float4 v0 = br[0], v1 = br[1], v2 = br[2], v3 = br[3];
            vals[0]=v0.x; vals[1]=v0.y; vals[2]=v0.z; vals[3]=v0.w;
            vals[4]=v1.x; vals[5]=v1.y; vals[6]=v1.z; vals[7]=v1.w;
            vals[8]=v2.x; vals[9]=v2.y; vals[10]=v2.z; vals[11]=v2.w;
            vals[12]=v3.x; vals[13]=v3.y; vals[14]=v3.z; vals[15]=v3.w;
        } else {
            #pragma unroll
            for (int o = 0; o < 16; ++o) vals[o] = 0.f;
        }
        #pragma unroll
        for (int o = 0; o < 16; ++o) bp[base + o * 8] = __float2half(vals[o]);
    }
    float* wf = reinterpret_cast<float*>(blob + BLOB_W1);
    wf[t]       = w1[t];
    wf[t + 256] = w1[t + 256];
    if (t < HID_D) reinterpret_cast<float*>(blob + BLOB_B1)[t] = b1[t];
}

// ---------------- edge kernel: MLP + phased MFMA + XCD-local atomic add ----------------

__global__ __launch_bounds__(256, 6) void edge_k(
    const float* __restrict__ x,
    const int*   __restrict__ ei,
    const float* __restrict__ ea,
    const unsigned char* __restrict__ gblob,
    int*   __restrict__ deg,
    float* __restrict__ sum)          // base of the 8 partial buffers
{
    __shared__ alignas(16) unsigned char s_blob[BLOB_BYTES];   // 20 KB
    __shared__ alignas(16) __half s_h2[4 * 16 * 32];           // 4 KB phase buf

    const int t    = threadIdx.x;
    const int lane = t & 63;
    const int w    = t >> 6;
    const int e    = blockIdx.x * 256 + t;   // grid exact

    // this workgroup's XCD -> its private partial buffer (uniform scalar)
    int xcc;
    asm("s_getreg_b32 %0, hwreg(HW_REG_XCC_ID)" : "=s"(xcc));
    float* sumx = sum + (size_t)(xcc & 7) * SUM_ELEMS;

    // ---- blob global->LDS: 20 x 1KB chunks across 4 waves
    #pragma unroll
    for (int j = 0; j < 5; ++j) {
        const int ch = w + 4 * j;            // 0..19
        gload_lds16(gblob + ch * 1024 + lane * 16, s_blob + ch * 1024);
    }

    const hfrag8* s_B  = reinterpret_cast<const hfrag8*>(s_blob);
    const float4* s_w1 = reinterpret_cast<const float4*>(s_blob + BLOB_W1);
    const float4* s_b1 = reinterpret_cast<const float4*>(s_blob + BLOB_B1);

    const int q   = lane >> 4;
    const int n   = lane & 15;
    const int qh  = q >> 1;
    const int i0q = (q & 1) * 8;
    const int swz = (lane >> 1) & 3;

    // ---- indices; deg count; ea + sub-0 x row prefetch before the barrier ----
    const int src = clampn(ei[e]);
    const int dst = clampn(ei[N_EDGES + e]);
    atomicAdd(&deg[dst], 1);                 // device-scope int (0.8M ops total)

    float eav[IN_D];
    {
        const float4* eap = reinterpret_cast<const float4*>(ea) + (size_t)e * 4;
        float4 a0 = eap[0], a1 = eap[1], a2 = eap[2], a3 = eap[3];
        eav[0]=a0.x;  eav[1]=a0.y;  eav[2]=a0.z;  eav[3]=a0.w;
        eav[4]=a1.x;  eav[5]=a1.y;  eav[6]=a1.z;  eav[7]=a1.w;
        eav[8]=a2.x;  eav[9]=a2.y;  eav[10]=a2.z; eav[11]=a2.w;
        eav[12]=a3.x; eav[13]=a3.y; eav[14]=a3.z; eav[15]=a3.w;
    }
    float4 xn0, xn1;                         // 1-ahead x pipeline
    {
        const int srcB = __shfl(src, n, 64); // sub 0
        const float4* xp = reinterpret_cast<const float4*>(x) + (size_t)srcB * 4 + (i0q >> 2);
        xn0 = xp[0]; xn1 = xp[1];
    }

    __syncthreads();            // drains vmcnt (global_load_lds) + makes blob visible

    // ---- edge MLP h = relu(ea@w1+b1) -> hp registers (64B row image) ----
    union { hfrag8 v[4]; __half h[32]; } hp;
    {
        float4 hv[HID_D / 4];
        #pragma unroll
        for (int j = 0; j < HID_D / 4; ++j) hv[j] = s_b1[j];
        #pragma unroll
        for (int i = 0; i < IN_D; ++i) {
            const float xi = eav[i];
            #pragma unroll
            for (int j = 0; j < HID_D / 4; ++j) fma4(xi, s_w1[i * (HID_D / 4) + j], hv[j]);
        }
        // logical row layout: h[k] at slot (k&1)*16 + (k>>1)
        #pragma unroll
        for (int jj = 0; jj < 8; ++jj) {
            const int k0 = 4 * jj;
            hp.h[((k0 + 0) & 1) * 16 + ((k0 + 0) >> 1)] = __float2half(fmaxf(hv[jj].x, 0.f));
            hp.h[((k0 + 1) & 1) * 16 + ((k0 + 1) >> 1)] = __float2half(fmaxf(hv[jj].y, 0.f));
            hp.h[((k0 + 2) & 1) * 16 + ((k0 + 2) >> 1)] = __float2half(fmaxf(hv[jj].z, 0.f));
            hp.h[((k0 + 3) & 1) * 16 + ((k0 + 3) >> 1)] = __float2half(fmaxf(hv[jj].w, 0.f));
        }
    }

    __half* hwav = reinterpret_cast<__half*>(s_h2) + w * 512;   // 1KB per wave

    // ---- 4 phases: {16 writers store row, wave_barrier, read 2xb128, MFMA, atomics} ----
    #pragma unroll
    for (int sub = 0; sub < 4; ++sub) {
        const float4 xa = xn0, xb = xn1;
        if (sub < 3) {                       // issue next phase's x row
            const int srcB = __shfl(src, (sub + 1) * 16 + n, 64);
            const float4* xp = reinterpret_cast<const float4*>(x) + (size_t)srcB * 4 + (i0q >> 2);
            xn0 = xp[0]; xn1 = xp[1];
        }
        // WAR guard: previous phase's reads complete before overwrite
        asm volatile("s_waitcnt lgkmcnt(0)" ::: "memory");
        __builtin_amdgcn_wave_barrier();
        if ((lane >> 4) == sub) {
            hfrag8* rowv = reinterpret_cast<hfrag8*>(hwav + (lane & 15) * 32);
            rowv[0 ^ swz] = hp.v[0];
            rowv[1 ^ swz] = hp.v[1];
            rowv[2 ^ swz] = hp.v[2];
            rowv[3 ^ swz] = hp.v[3];
        }
        asm volatile("s_waitcnt lgkmcnt(0)" ::: "memory");
        __builtin_amdgcn_wave_barrier();

        union { hfrag8 v; __half h[8]; } hA, hB;   // tiles 0-7 / 8-15 for this qh
        {
            const hfrag8* rowv = reinterpret_cast<const hfrag8*>(hwav + n * 32);
            hA.v = rowv[(2 * qh + 0) ^ swz];
            hB.v = rowv[(2 * qh + 1) ^ swz];
        }
        __half2 xh[4];
        xh[0] = __float22half2_rn(make_float2(xa.x, xa.y));
        xh[1] = __float22half2_rn(make_float2(xa.z, xa.w));
        xh[2] = __float22half2_rn(make_float2(xb.x, xb.y));
        xh[3] = __float22half2_rn(make_float2(xb.z, xb.w));

        f32x4 acc = {0.f, 0.f, 0.f, 0.f};
        #pragma unroll
        for (int tile = 0; tile < 16; ++tile) {
            const __half hs = (tile < 8) ? hA.h[tile] : hB.h[tile - 8];   // h[2*tile+qh]
            const __half2 hh = __half2half2(hs);
            union { hfrag8 v; __half2 h[4]; } a;
            a.h[0] = __hmul2(hh, xh[0]);
            a.h[1] = __hmul2(hh, xh[1]);
            a.h[2] = __hmul2(hh, xh[2]);
            a.h[3] = __hmul2(hh, xh[3]);
            acc = __builtin_amdgcn_mfma_f32_16x16x32_f16(a.v, s_B[tile * 64 + lane], acc, 0, 0, 0);
        }
        {   // b2 tile: A = x (qh==0) / 0 (qh==1)
            union { hfrag8 v; __half2 h[4]; } a;
            if (qh == 0) { a.h[0]=xh[0]; a.h[1]=xh[1]; a.h[2]=xh[2]; a.h[3]=xh[3]; }
            else { hfrag8 z = {0,0,0,0,0,0,0,0}; a.v = z; }
            acc = __builtin_amdgcn_mfma_f32_16x16x32_f16(a.v, s_B[16 * 64 + lane], acc, 0, 0, 0);
        }
        // XCD-local L2 atomic add into this XCD's private partial buffer
        #pragma unroll
        for (int r = 0; r < 4; ++r) {
            const int dstB = __shfl(dst, sub * 16 + q * 4 + r, 64);
            xcdAtomicAdd(&sumx[(size_t)dstB * 16 + n], acc[r]);
        }
    }
}

// ---------------- node kernel: out = (sum of 8 partials)/deg + x@root + bias ----------------

__global__ __launch_bounds__(256) void node_k(
    const float* __restrict__ x,
    const float* __restrict__ root,
    const float* __restrict__ bias,
    const float* __restrict__ sum,    // 8 partial buffers
    const int*   __restrict__ deg,
    float* __restrict__ out)
{
    __shared__ float s_root[IN_D * OUT_D];
    __shared__ float s_bias[OUT_D];
    const int t = threadIdx.x;
    s_root[t] = root[t];
    if (t < OUT_D) s_bias[t] = bias[t];
    __syncthreads();

    const int g = blockIdx.x * 256 + t;      // grid exact: 3125*256 = 50000*16
    const int n = g >> 4;
    const int o = g & 15;

    float s = 0.f;
    #pragma unroll
    for (int xc = 0; xc < NXCD; ++xc)
        s += sum[(size_t)xc * SUM_ELEMS + g];

    const int d = deg[n];
    float mv = s * (1.0f / (float)(d > 1 ? d : 1)) + s_bias[o];

    float xs[IN_D];
    {
        const float4* xp = reinterpret_cast<const float4*>(x) + (size_t)n * 4;
        float4 b0 = xp[0], b1v = xp[1], b2v = xp[2], b3 = xp[3];
        xs[0]=b0.x;  xs[1]=b0.y;  xs[2]=b0.z;  xs[3]=b0.w;
        xs[4]=b1v.x; xs[5]=b1v.y; xs[6]=b1v.z; xs[7]=b1v.w;
        xs[8]=b2v.x; xs[9]=b2v.y; xs[10]=b2v.z; xs[11]=b2v.w;
        xs[12]=b3.x; xs[13]=b3.y; xs[14]=b3.z; xs[15]=b3.w;
    }
    #pragma unroll
    for (int i = 0; i < IN_D; ++i)
        mv = fmaf(xs[i], s_root[i * OUT_D + o], mv);

    out[g] = mv;
}

extern "C" void kernel_launch(void* const* d_in, const int* in_sizes, int n_in,
                              void* d_out, int out_size, void* d_ws, size_t ws_size,
                              hipStream_t stream) {
    const float* x    = (const float*)d_in[0];
    const int*   ei   = (const int*)  d_in[1];
    const float* ea   = (const float*)d_in[2];
    const float* w1   = (const float*)d_in[3];
    const float* b1   = (const float*)d_in[4];
    const float* w2   = (const float*)d_in[5];
    const float* b2   = (const float*)d_in[6];
    const float* root = (const float*)d_in[7];
    const float* bias = (const float*)d_in[8];
    float* out = (float*)d_out;

    unsigned char* ws   = (unsigned char*)d_ws;
    unsigned char* blob = ws;
    float* sum = (float*)(ws + WS_SUM);      // 8 x N*16 f32 partials
    int*   deg = (int*)(ws + WS_DEG);        // N ints

    // zero 8 partials + deg in one contiguous memset (~25.8MB)
    hipMemsetAsync(ws + WS_SUM, 0,
                   (size_t)NXCD * SUM_ELEMS * 4 + (size_t)N_NODES * 4, stream);
    setup_k<<<1, 256, 0, stream>>>(w1, b1, w2, b2, blob);
    edge_k<<<NBLK_E, 256, 0, stream>>>(x, ei, ea, blob, deg, sum);
    node_k<<<NBLK_N, 256, 0, stream>>>(x, root, bias, sum, deg, out);
}

// Round 7
// 184.621 us; speedup vs baseline: 1.0404x; 1.0404x over previous
//
#include <hip/hip_runtime.h>
#include <hip/hip_bf16.h>
#include <hip/hip_fp16.h>

// NNConv R20: consolidation. R19 post-mortem: scope-less atomics to XCD-
// private buffers gave BYTE-IDENTICAL WRITE_SIZE (87.405MB) and dur (84us) vs
// device-scope single-buffer -> on gfx950 f32 atomic adds resolve at the same
// memory-side point regardless of sc bits/locality; no HIP-level lever there.
// R17/18/19 = 184.3/184.0/192.1 with edge pinned 83-85 across occupancy +44%,
// atomic locality, write locality -> plateau is the atomic epilogue (~+15us
// over stores, still cheaper than CSR's ~40us aux) + ~88us harness reset
// (dozens of tiny restore dispatches inside the measured region, per skill
// doc). This round: revert R19's 8-partial overhead (single sum, 3.4MB
// memset, node reads 6.6MB: -7us), drop the pre-write LDS drain per phase
// (WAR safe: same-wave DS is in-order + overlapping-address analysis; keeps
// post-write RAW drain) = 4 fewer full lgkmcnt(0)/wave, s_setprio(1) around
// the MFMA cluster (T5; blocks phase-staggered on CU -> role diversity),
// deg atomic deferred after prefetch issues.
// Pre-commit: edge >=82 && total >=183 -> structural plateau, declare next.

#define N_NODES 50000
#define N_EDGES 800000
#define IN_D    16
#define OUT_D   16
#define HID_D   32
#define KTILES  17
#define NBLK_E  (N_EDGES / 256)            // 3125, exact
#define NBLK_N  (N_NODES * OUT_D / 256)    // 3125, exact
#define BLOB_BYTES 20480                   // 20 x 1KB chunks
#define BLOB_W1    17408                   // s_B image [0,17408)
#define BLOB_B1    19456                   // w1 [17408,19456), b1 [19456,19584)

// ws layout (byte offsets)
#define WS_SUM   20480                     // N*16 f32 = 3.2MB
#define WS_DEG   3220480                   // N ints = 200KB
#define WS_NEED  (3220480 + (size_t)N_NODES * 4)   // ~3.42MB

typedef __attribute__((ext_vector_type(8))) _Float16 hfrag8;
typedef __attribute__((ext_vector_type(4))) float f32x4;

__device__ __forceinline__ void fma4(float a, const float4 w, float4& m) {
    m.x = fmaf(a, w.x, m.x);
    m.y = fmaf(a, w.y, m.y);
    m.z = fmaf(a, w.z, m.z);
    m.w = fmaf(a, w.w, m.w);
}
__device__ __forceinline__ int clampn(int v) {
    return v < 0 ? 0 : (v >= N_NODES ? N_NODES - 1 : v);
}
__device__ __forceinline__ void gload_lds16(const void* g, void* l) {
    __builtin_amdgcn_global_load_lds(
        (const __attribute__((address_space(1))) unsigned int*)g,
        (__attribute__((address_space(3))) unsigned int*)l,
        16, 0, 0);
}

// ---------------- one-block setup: build {s_B f16 image, w1, b1} blob ----------------

__global__ __launch_bounds__(256) void setup_k(
    const float* __restrict__ w1,
    const float* __restrict__ b1,
    const float* __restrict__ w2,
    const float* __restrict__ b2,
    unsigned char* __restrict__ blob)
{
    const int t = threadIdx.x;
    __half* bp = reinterpret_cast<__half*>(blob);
    for (int r = t; r < KTILES * 32; r += 256) {
        const int tile = r >> 5, q = (r >> 3) & 3, j = r & 7;
        const int base = ((tile * 4 + q) * 16) * 8 + j;
        float vals[16];
        if (r < 512) {
            const float4* wr = reinterpret_cast<const float4*>(w2) + r * 4;
            float4 v0 = wr[0], v1 = wr[1], v2 = wr[2], v3 = wr[3];
            vals[0]=v0.x; vals[1]=v0.y; vals[2]=v0.z; vals[3]=v0.w;
            vals[4]=v1.x; vals[5]=v1.y; vals[6]=v1.z; vals[7]=v1.w;
            vals[8]=v2.x; vals[9]=v2.y; vals[10]=v2.z; vals[11]=v2.w;
            vals[12]=v3.x; vals[13]=v3.y; vals[14]=v3.z; vals[15]=v3.w;
        } else if (r < 528) {
            const float4* br = reinterpret_cast<const float4*>(b2) + (r - 512) * 4;
            float4 v0 = br[0], v1 = br[1], v2 = br[2], v3 = br[3];
            vals[0]=v0.x; vals[1]=v0.y; vals[2]=v0.z; vals[3]=v0.w;
            vals[4]=v1.x; vals[5]=v1.y; vals[6]=v1.z; vals[7]=v1.w;
            vals[8]=v2.x; vals[9]=v2.y; vals[10]=v2.z; vals[11]=v2.w;
            vals[12]=v3.x; vals[13]=v3.y; vals[14]=v3.z; vals[15]=v3.w;
        } else {
            #pragma unroll
            for (int o = 0; o < 16; ++o) vals[o] = 0.f;
        }
        #pragma unroll
        for (int o = 0; o < 16; ++o) bp[base + o * 8] = __float2half(vals[o]);
    }
    float* wf = reinterpret_cast<float*>(blob + BLOB_W1);
    wf[t]       = w1[t];
    wf[t + 256] = w1[t + 256];
    if (t < HID_D) reinterpret_cast<float*>(blob + BLOB_B1)[t] = b1[t];
}

// ---------------- edge kernel: MLP + phased MFMA + atomic scatter-add ----------------

__global__ __launch_bounds__(256, 6) void edge_k(
    const float* __restrict__ x,
    const int*   __restrict__ ei,
    const float* __restrict__ ea,
    const unsigned char* __restrict__ gblob,
    int*   __restrict__ deg,
    float* __restrict__ sum)
{
    __shared__ alignas(16) unsigned char s_blob[BLOB_BYTES];   // 20 KB
    __shared__ alignas(16) __half s_h2[4 * 16 * 32];           // 4 KB phase buf

    const int t    = threadIdx.x;
    const int lane = t & 63;
    const int w    = t >> 6;
    const int e    = blockIdx.x * 256 + t;   // grid exact

    // ---- blob global->LDS: 20 x 1KB chunks across 4 waves
    #pragma unroll
    for (int j = 0; j < 5; ++j) {
        const int ch = w + 4 * j;            // 0..19
        gload_lds16(gblob + ch * 1024 + lane * 16, s_blob + ch * 1024);
    }

    const hfrag8* s_B  = reinterpret_cast<const hfrag8*>(s_blob);
    const float4* s_w1 = reinterpret_cast<const float4*>(s_blob + BLOB_W1);
    const float4* s_b1 = reinterpret_cast<const float4*>(s_blob + BLOB_B1);

    const int q   = lane >> 4;
    const int n   = lane & 15;
    const int qh  = q >> 1;
    const int i0q = (q & 1) * 8;
    const int swz = (lane >> 1) & 3;

    // ---- indices; ea + sub-0 x prefetch first, deg atomic after (issue order) ----
    const int src = clampn(ei[e]);
    const int dst = clampn(ei[N_EDGES + e]);

    float eav[IN_D];
    {
        const float4* eap = reinterpret_cast<const float4*>(ea) + (size_t)e * 4;
        float4 a0 = eap[0], a1 = eap[1], a2 = eap[2], a3 = eap[3];
        eav[0]=a0.x;  eav[1]=a0.y;  eav[2]=a0.z;  eav[3]=a0.w;
        eav[4]=a1.x;  eav[5]=a1.y;  eav[6]=a1.z;  eav[7]=a1.w;
        eav[8]=a2.x;  eav[9]=a2.y;  eav[10]=a2.z; eav[11]=a2.w;
        eav[12]=a3.x; eav[13]=a3.y; eav[14]=a3.z; eav[15]=a3.w;
    }
    float4 xn0, xn1;                         // 1-ahead x pipeline
    {
        const int srcB = __shfl(src, n, 64); // sub 0
        const float4* xp = reinterpret_cast<const float4*>(x) + (size_t)srcB * 4 + (i0q >> 2);
        xn0 = xp[0]; xn1 = xp[1];
    }
    atomicAdd(&deg[dst], 1);                 // fire-and-forget, retires during MLP

    __syncthreads();            // drains vmcnt (global_load_lds) + makes blob visible

    // ---- edge MLP h = relu(ea@w1+b1) -> hp registers (64B row image) ----
    union { hfrag8 v[4]; __half h[32]; } hp;
    {
        float4 hv[HID_D / 4];
        #pragma unroll
        for (int j = 0; j < HID_D / 4; ++j) hv[j] = s_b1[j];
        #pragma unroll
        for (int i = 0; i < IN_D; ++i) {
            const float xi = eav[i];
            #pragma unroll
            for (int j = 0; j < HID_D / 4; ++j) fma4(xi, s_w1[i * (HID_D / 4) + j], hv[j]);
        }
        // logical row layout: h[k] at slot (k&1)*16 + (k>>1)
        #pragma unroll
        for (int jj = 0; jj < 8; ++jj) {
            const int k0 = 4 * jj;
            hp.h[((k0 + 0) & 1) * 16 + ((k0 + 0) >> 1)] = __float2half(fmaxf(hv[jj].x, 0.f));
            hp.h[((k0 + 1) & 1) * 16 + ((k0 + 1) >> 1)] = __float2half(fmaxf(hv[jj].y, 0.f));
            hp.h[((k0 + 2) & 1) * 16 + ((k0 + 2) >> 1)] = __float2half(fmaxf(hv[jj].z, 0.f));
            hp.h[((k0 + 3) & 1) * 16 + ((k0 + 3) >> 1)] = __float2half(fmaxf(hv[jj].w, 0.f));
        }
    }

    __half* hwav = reinterpret_cast<__half*>(s_h2) + w * 512;   // 1KB per wave

    // ---- 4 phases: {16 writers store row, drain+barrier, read 2xb128, MFMA, atomics}
    // WAR on the previous phase's reads is safe WITHOUT a pre-write drain:
    // same-wave DS ops execute in order, and write/read rows share the same
    // base expression so the compiler preserves program order.
    #pragma unroll
    for (int sub = 0; sub < 4; ++sub) {
        const float4 xa = xn0, xb = xn1;
        if (sub < 3) {                       // issue next phase's x row
            const int srcB = __shfl(src, (sub + 1) * 16 + n, 64);
            const float4* xp = reinterpret_cast<const float4*>(x) + (size_t)srcB * 4 + (i0q >> 2);
            xn0 = xp[0]; xn1 = xp[1];
        }
        if ((lane >> 4) == sub) {
            hfrag8* rowv = reinterpret_cast<hfrag8*>(hwav + (lane & 15) * 32);
            rowv[0 ^ swz] = hp.v[0];
            rowv[1 ^ swz] = hp.v[1];
            rowv[2 ^ swz] = hp.v[2];
            rowv[3 ^ swz] = hp.v[3];
        }
        // RAW: writes visible to all lanes of this wave before the reads
        asm volatile("s_waitcnt lgkmcnt(0)" ::: "memory");
        __builtin_amdgcn_wave_barrier();

        union { hfrag8 v; __half h[8]; } hA, hB;   // tiles 0-7 / 8-15 for this qh
        {
            const hfrag8* rowv = reinterpret_cast<const hfrag8*>(hwav + n * 32);
            hA.v = rowv[(2 * qh + 0) ^ swz];
            hB.v = rowv[(2 * qh + 1) ^ swz];
        }
        __half2 xh[4];
        xh[0] = __float22half2_rn(make_float2(xa.x, xa.y));
        xh[1] = __float22half2_rn(make_float2(xa.z, xa.w));
        xh[2] = __float22half2_rn(make_float2(xb.x, xb.y));
        xh[3] = __float22half2_rn(make_float2(xb.z, xb.w));

        f32x4 acc = {0.f, 0.f, 0.f, 0.f};
        __builtin_amdgcn_s_setprio(1);
        #pragma unroll
        for (int tile = 0; tile < 16; ++tile) {
            const __half hs = (tile < 8) ? hA.h[tile] : hB.h[tile - 8];   // h[2*tile+qh]
            const __half2 hh = __half2half2(hs);
            union { hfrag8 v; __half2 h[4]; } a;
            a.h[0] = __hmul2(hh, xh[0]);
            a.h[1] = __hmul2(hh, xh[1]);
            a.h[2] = __hmul2(hh, xh[2]);
            a.h[3] = __hmul2(hh, xh[3]);
            acc = __builtin_amdgcn_mfma_f32_16x16x32_f16(a.v, s_B[tile * 64 + lane], acc, 0, 0, 0);
        }
        {   // b2 tile: A = x (qh==0) / 0 (qh==1)
            union { hfrag8 v; __half2 h[4]; } a;
            if (qh == 0) { a.h[0]=xh[0]; a.h[1]=xh[1]; a.h[2]=xh[2]; a.h[3]=xh[3]; }
            else { hfrag8 z = {0,0,0,0,0,0,0,0}; a.v = z; }
            acc = __builtin_amdgcn_mfma_f32_16x16x32_f16(a.v, s_B[16 * 64 + lane], acc, 0, 0, 0);
        }
        __builtin_amdgcn_s_setprio(0);

        // hardware f32 atomic add into the owning node's sum row
        #pragma unroll
        for (int r = 0; r < 4; ++r) {
            const int dstB = __shfl(dst, sub * 16 + q * 4 + r, 64);
            unsafeAtomicAdd(&sum[(size_t)dstB * 16 + n], acc[r]);
        }
    }
}

// ---------------- node kernel: out = sum/deg + x@root + bias ----------------

__global__ __launch_bounds__(256) void node_k(
    const float* __restrict__ x,
    const float* __restrict__ root,
    const float* __restrict__ bias,
    const float* __restrict__ sum,
    const int*   __restrict__ deg,
    float* __restrict__ out)
{
    __shared__ float s_root[IN_D * OUT_D];
    __shared__ float s_bias[OUT_D];
    const int t = threadIdx.x;
    s_root[t] = root[t];
    if (t < OUT_D) s_bias[t] = bias[t];
    __syncthreads();

    const int g = blockIdx.x * 256 + t;      // grid exact: 3125*256 = 50000*16
    const int n = g >> 4;
    const int o = g & 15;

    const float s = sum[g];
    const int   d = deg[n];
    float mv = s * (1.0f / (float)(d > 1 ? d : 1)) + s_bias[o];

    float xs[IN_D];
    {
        const float4* xp = reinterpret_cast<const float4*>(x) + (size_t)n * 4;
        float4 b0 = xp[0], b1v = xp[1], b2v = xp[2], b3 = xp[3];
        xs[0]=b0.x;  xs[1]=b0.y;  xs[2]=b0.z;  xs[3]=b0.w;
        xs[4]=b1v.x; xs[5]=b1v.y; xs[6]=b1v.z; xs[7]=b1v.w;
        xs[8]=b2v.x; xs[9]=b2v.y; xs[10]=b2v.z; xs[11]=b2v.w;
        xs[12]=b3.x; xs[13]=b3.y; xs[14]=b3.z; xs[15]=b3.w;
    }
    #pragma unroll
    for (int i = 0; i < IN_D; ++i)
        mv = fmaf(xs[i], s_root[i * OUT_D + o], mv);

    out[g] = mv;
}

extern "C" void kernel_launch(void* const* d_in, const int* in_sizes, int n_in,
                              void* d_out, int out_size, void* d_ws, size_t ws_size,
                              hipStream_t stream) {
    const float* x    = (const float*)d_in[0];
    const int*   ei   = (const int*)  d_in[1];
    const float* ea   = (const float*)d_in[2];
    const float* w1   = (const float*)d_in[3];
    const float* b1   = (const float*)d_in[4];
    const float* w2   = (const float*)d_in[5];
    const float* b2   = (const float*)d_in[6];
    const float* root = (const float*)d_in[7];
    const float* bias = (const float*)d_in[8];
    float* out = (float*)d_out;

    unsigned char* ws   = (unsigned char*)d_ws;
    unsigned char* blob = ws;
    float* sum = (float*)(ws + WS_SUM);      // N*16 f32, 3.2MB
    int*   deg = (int*)(ws + WS_DEG);        // N ints

    // zero sum+deg in one contiguous memset (3.4MB)
    hipMemsetAsync(ws + WS_SUM, 0, (size_t)N_NODES * 16 * 4 + (size_t)N_NODES * 4, stream);
    setup_k<<<1, 256, 0, stream>>>(w1, b1, w2, b2, blob);
    edge_k<<<NBLK_E, 256, 0, stream>>>(x, ei, ea, blob, deg, sum);
    node_k<<<NBLK_N, 256, 0, stream>>>(x, root, bias, sum, deg, out);
}